// Round 1
// baseline (21290.451 us; speedup 1.0000x reference)
//
#include <hip/hip_runtime.h>
#include <math.h>

// ---------------- model constants ----------------
// HD=256 NL=4 NH=8 DH=32 MP=8 MS=32 T=40 ES=64 BATCH=8 BEAMS=5 BB=40
// START=1 END=2 MIN_LL_PEN=-100000

// ---------------- block reduction ----------------
__device__ __forceinline__ float blockSum256(float v, float* red) {
#pragma unroll
  for (int off = 32; off >= 1; off >>= 1) v += __shfl_xor(v, off);
  __syncthreads();                       // protect red from previous use
  if ((threadIdx.x & 63) == 0) red[threadIdx.x >> 6] = v;
  __syncthreads();
  return red[0] + red[1] + red[2] + red[3];
}

// ---------------- conv kernels ----------------
// Generic: one block handles a 256-element spatial chunk of one (b, oc).
// Weights for this oc staged in LDS. stride 2, kernel 4, pad 1.
template <int IC, int OC, int OD, int CHUNKS>
__global__ __launch_bounds__(256) void conv_v1(const float* __restrict__ in,
                                               const float* __restrict__ w,
                                               const float* __restrict__ bias,
                                               float* __restrict__ out) {
  constexpr int ID = OD * 2;
  constexpr int ID2 = ID * ID;
  __shared__ float wl[IC * 64];
  int bi = blockIdx.x;
  int chunk = bi % CHUNKS;
  int oc = (bi / CHUNKS) % OC;
  int b = bi / (CHUNKS * OC);
  for (int i = threadIdx.x; i < IC * 64; i += 256) wl[i] = w[oc * IC * 64 + i];
  __syncthreads();
  int s = chunk * 256 + threadIdx.x;
  if (s >= OD * OD * OD) return;
  int od = s / (OD * OD), oh = (s / OD) % OD, ow = s % OD;
  float acc = 0.f;
  for (int ic = 0; ic < IC; ++ic) {
    const float* ipb = in + (size_t)(b * IC + ic) * (ID * ID2);
    const float* wp = wl + ic * 64;
#pragma unroll
    for (int kd = 0; kd < 4; ++kd) {
      int id = od * 2 - 1 + kd;
      if ((unsigned)id < (unsigned)ID) {
#pragma unroll
        for (int kh = 0; kh < 4; ++kh) {
          int ih = oh * 2 - 1 + kh;
          if ((unsigned)ih < (unsigned)ID) {
            const float* rowp = ipb + id * ID2 + ih * ID;
#pragma unroll
            for (int kw = 0; kw < 4; ++kw) {
              int iw = ow * 2 - 1 + kw;
              if ((unsigned)iw < (unsigned)ID)
                acc = fmaf(rowp[iw], wp[kd * 16 + kh * 4 + kw], acc);
            }
          }
        }
      }
    }
  }
  acc += bias[oc];
  out[((size_t)(b * OC + oc) * OD + od) * (OD * OD) + oh * OD + ow] = fmaxf(acc, 0.f);
}

// conv4: IC=128 OC=256 OD=4 (64 spatial). One 64-thread block per (b,oc).
__global__ __launch_bounds__(64) void conv_v2(const float* __restrict__ in,
                                              const float* __restrict__ w,
                                              const float* __restrict__ bias,
                                              float* __restrict__ out) {
  constexpr int IC = 128, OD = 4, ID = 8, ID2 = 64;
  __shared__ float wl[IC * 64];  // 32KB
  int oc = blockIdx.x % 256;
  int b = blockIdx.x / 256;
  for (int i = threadIdx.x; i < IC * 64; i += 64) wl[i] = w[oc * IC * 64 + i];
  __syncthreads();
  int s = threadIdx.x;
  int od = s >> 4, oh = (s >> 2) & 3, ow = s & 3;
  float acc = 0.f;
  for (int ic = 0; ic < IC; ++ic) {
    const float* ipb = in + (size_t)(b * IC + ic) * (ID * ID2);
    const float* wp = wl + ic * 64;
#pragma unroll
    for (int kd = 0; kd < 4; ++kd) {
      int id = od * 2 - 1 + kd;
      if ((unsigned)id < (unsigned)ID) {
#pragma unroll
        for (int kh = 0; kh < 4; ++kh) {
          int ih = oh * 2 - 1 + kh;
          if ((unsigned)ih < (unsigned)ID) {
            const float* rowp = ipb + id * ID2 + ih * ID;
#pragma unroll
            for (int kw = 0; kw < 4; ++kw) {
              int iw = ow * 2 - 1 + kw;
              if ((unsigned)iw < (unsigned)ID)
                acc = fmaf(rowp[iw], wp[kd * 16 + kh * 4 + kw], acc);
            }
          }
        }
      }
    }
  }
  acc += bias[oc];
  out[((size_t)(b * 256 + oc) * OD + od) * 16 + oh * 4 + ow] = fmaxf(acc, 0.f);
}

// conv5: IC=256 OC=256 OD=2 (8 spatial). Input for one b staged in LDS (64KB).
// Block = 256 threads = 32 oc x 8 spatial; grid = 8 b x 8 oc-groups.
// Writes directly in codes layout: codes[(b*8 + p)*256 + oc].
__global__ __launch_bounds__(256) void conv_v3(const float* __restrict__ in,
                                               const float* __restrict__ w,
                                               const float* __restrict__ bias,
                                               float* __restrict__ codes) {
  __shared__ float inl[256 * 64];  // 64KB: [ic][4][4][4]
  int b = blockIdx.x >> 3;
  int ocg = blockIdx.x & 7;
  for (int i = threadIdx.x; i < 256 * 64; i += 256) inl[i] = in[b * 256 * 64 + i];
  __syncthreads();
  int oc = ocg * 32 + (threadIdx.x >> 3);
  int s = threadIdx.x & 7;
  int od = s >> 2, oh = (s >> 1) & 1, ow = s & 1;
  const float* wp = w + (size_t)oc * 256 * 64;
  float acc = 0.f;
  for (int ic = 0; ic < 256; ++ic) {
    const float* ib = inl + ic * 64;
    const float* wb = wp + ic * 64;
#pragma unroll
    for (int kd = 0; kd < 4; ++kd) {
      int id = od * 2 - 1 + kd;
      if ((unsigned)id < 4u) {
#pragma unroll
        for (int kh = 0; kh < 4; ++kh) {
          int ih = oh * 2 - 1 + kh;
          if ((unsigned)ih < 4u) {
#pragma unroll
            for (int kw = 0; kw < 4; ++kw) {
              int iw = ow * 2 - 1 + kw;
              if ((unsigned)iw < 4u)
                acc = fmaf(ib[id * 16 + ih * 4 + iw], wb[kd * 16 + kh * 4 + kw], acc);
            }
          }
        }
      }
    }
  }
  acc += bias[oc];
  codes[(b * 8 + s) * 256 + oc] = fmaxf(acc, 0.f);
}

// ---------------- decode state init ----------------
__global__ void k_init(int* __restrict__ bseqs, float* __restrict__ blls,
                       int* __restrict__ ptr) {
  int t = blockIdx.x * 256 + threadIdx.x;
  if (t < 1280) bseqs[t] = ((t & 31) == 0) ? 1 : 0;  // START=1 at pos 0
  if (t < 40) blls[t] = (t % 5 == 0) ? 0.f : -100000.0f;
  if (t < 1600) ptr[t] = t / 40;  // identity ancestry
}

// ---------------- transformer step (one WG per beam) ----------------
// ti=0: prefill rows 0..8.  ti>0: only row 8+ti.  Writes logits[bb][64].
__global__ __launch_bounds__(256) void k_step(
    int ti, const float* __restrict__ codes, float* __restrict__ Kc,
    float* __restrict__ Vc, float* __restrict__ logits,
    const int* __restrict__ bseqs, const int* __restrict__ ptr,
    const float* __restrict__ tok_emb, const float* __restrict__ pos_emb,
    const float* __restrict__ Wqkv, const float* __restrict__ Wo,
    const float* __restrict__ ln1s, const float* __restrict__ ln1b,
    const float* __restrict__ ln2s, const float* __restrict__ ln2b,
    const float* __restrict__ Wff1, const float* __restrict__ bff1,
    const float* __restrict__ Wff2, const float* __restrict__ bff2,
    const float* __restrict__ hW1, const float* __restrict__ hb1,
    const float* __restrict__ hW2, const float* __restrict__ hb2) {
  const int bb = blockIdx.x;
  const int b = bb / 5;
  const int t = threadIdx.x;
  const int r1 = 8 + ti;
  const int r0 = (ti == 0) ? 0 : r1;
  const int NR = r1 - r0 + 1;  // <= 9

  __shared__ float xs[9][256];
  __shared__ float qs[9][256];
  __shared__ float hs[256];
  __shared__ float aos[256];
  __shared__ float f1s[1024];
  __shared__ float scs[8][40];
  __shared__ float red[4];
  __shared__ int ips[40];

  if (t < 40) ips[t] = ptr[bb * 40 + t];
  // embedding
  for (int ri = 0; ri < NR; ++ri) {
    int row = r0 + ri;
    float v;
    if (row < 8) {
      v = codes[(b * 8 + row) * 256 + t];
    } else {
      int tok = bseqs[bb * 32 + (row - 8)];
      v = tok_emb[tok * 256 + t];
    }
    xs[ri][t] = v + pos_emb[row * 256 + t];
  }
  __syncthreads();

  for (int l = 0; l < 4; ++l) {
    const float* Wq = Wqkv + (size_t)l * 256 * 768;
    // ---- LN1 + QKV, write K/V caches ----
    for (int ri = 0; ri < NR; ++ri) {
      float xv = xs[ri][t];
      float mean = blockSum256(xv, red) * (1.f / 256.f);
      float dv = xv - mean;
      float var = blockSum256(dv * dv, red) * (1.f / 256.f);
      float rsd = 1.f / sqrtf(var + 1e-5f);
      hs[t] = dv * rsd * ln1s[l * 256 + t] + ln1b[l * 256 + t];
      __syncthreads();
      float a0 = 0.f, a1 = 0.f, a2 = 0.f;
#pragma unroll 8
      for (int k = 0; k < 256; ++k) {
        float hk = hs[k];
        const float* wr = Wq + k * 768;
        a0 = fmaf(hk, wr[t], a0);
        a1 = fmaf(hk, wr[256 + t], a1);
        a2 = fmaf(hk, wr[512 + t], a2);
      }
      int row = r0 + ri;
      qs[ri][t] = a0;
      Kc[((size_t)(l * 40 + bb) * 40 + row) * 256 + t] = a1;
      Vc[((size_t)(l * 40 + bb) * 40 + row) * 256 + t] = a2;
      __syncthreads();
    }
    // ---- attention + proj + residual + LN2 + FF, per row ----
    for (int ri = 0; ri < NR; ++ri) {
      int row = r0 + ri;
      int g = t >> 5, d = t & 31;
      for (int jj = d; jj <= row; jj += 32) {
        const float* kp = Kc + ((size_t)(l * 40 + ips[jj]) * 40 + jj) * 256 + g * 32;
        float s = 0.f;
#pragma unroll
        for (int dd = 0; dd < 32; ++dd) s = fmaf(qs[ri][g * 32 + dd], kp[dd], s);
        scs[g][jj] = s * 0.17677669529663687f;  // 1/sqrt(32)
      }
      __syncthreads();
      float m = -3.4e38f;
      for (int j = 0; j <= row; ++j) m = fmaxf(m, scs[g][j]);
      float sum = 0.f;
      for (int j = 0; j <= row; ++j) sum += expf(scs[g][j] - m);
      float o = 0.f;
      for (int j = 0; j <= row; ++j) {
        float p = expf(scs[g][j] - m) / sum;
        o = fmaf(p, Vc[((size_t)(l * 40 + ips[j]) * 40 + j) * 256 + g * 32 + d], o);
      }
      aos[t] = o;
      __syncthreads();
      const float* Wop = Wo + (size_t)l * 256 * 256;
      float a = 0.f;
#pragma unroll 8
      for (int k = 0; k < 256; ++k) a = fmaf(aos[k], Wop[k * 256 + t], a);
      float xv = xs[ri][t] + a;
      xs[ri][t] = xv;
      float mean = blockSum256(xv, red) * (1.f / 256.f);
      float dv = xv - mean;
      float var = blockSum256(dv * dv, red) * (1.f / 256.f);
      float rsd = 1.f / sqrtf(var + 1e-5f);
      hs[t] = dv * rsd * ln2s[l * 256 + t] + ln2b[l * 256 + t];
      __syncthreads();
      const float* W1 = Wff1 + (size_t)l * 256 * 1024;
      float c0 = 0.f, c1 = 0.f, c2 = 0.f, c3 = 0.f;
#pragma unroll 8
      for (int k = 0; k < 256; ++k) {
        float hk = hs[k];
        const float* wr = W1 + k * 1024;
        c0 = fmaf(hk, wr[t], c0);
        c1 = fmaf(hk, wr[256 + t], c1);
        c2 = fmaf(hk, wr[512 + t], c2);
        c3 = fmaf(hk, wr[768 + t], c3);
      }
      const float* b1 = bff1 + l * 1024;
      f1s[t] = fmaxf(c0 + b1[t], 0.f);
      f1s[256 + t] = fmaxf(c1 + b1[256 + t], 0.f);
      f1s[512 + t] = fmaxf(c2 + b1[512 + t], 0.f);
      f1s[768 + t] = fmaxf(c3 + b1[768 + t], 0.f);
      __syncthreads();
      const float* W2 = Wff2 + (size_t)l * 1024 * 256;
      float a2 = 0.f;
#pragma unroll 8
      for (int k = 0; k < 1024; ++k) a2 = fmaf(f1s[k], W2[k * 256 + t], a2);
      xs[ri][t] = xs[ri][t] + a2 + bff2[l * 256 + t];
      __syncthreads();
    }
  }
  // ---- head on last row ----
  {
    int ri = NR - 1;
    float a = 0.f;
#pragma unroll 8
    for (int k = 0; k < 256; ++k) a = fmaf(xs[ri][k], hW1[k * 256 + t], a);
    f1s[t] = fmaxf(a + hb1[t], 0.f);
    __syncthreads();
    if (t < 64) {
      float lgv = 0.f;
#pragma unroll 8
      for (int k = 0; k < 256; ++k) lgv = fmaf(f1s[k], hW2[k * 64 + t], lgv);
      logits[bb * 64 + t] = lgv + hb2[t];
    }
  }
}

// ---------------- beam update (single WG, exact tie semantics) ----------------
__global__ __launch_bounds__(256) void k_beam(int ti, const float* __restrict__ logits,
                                              int* __restrict__ bseqs,
                                              float* __restrict__ blls,
                                              int* __restrict__ ptr) {
  __shared__ float lg[40][64];
  __shared__ float bdist[40][64];
  __shared__ float rm[40], rsum[40];
  __shared__ float bd[40][5];
  __shared__ int bc[40][5];
  __shared__ float oll[40], nll[40];
  __shared__ int nts[40], oldx[40];
  __shared__ int oseq[40][32];
  __shared__ int optr[40][40];
  int t = threadIdx.x;
  for (int i = t; i < 2560; i += 256) ((float*)lg)[i] = logits[i];
  for (int i = t; i < 1280; i += 256) ((int*)oseq)[i] = bseqs[i];
  for (int i = t; i < 1600; i += 256) ((int*)optr)[i] = ptr[i];
  if (t < 40) oll[t] = blls[t];
  __syncthreads();
  if (t < 40) {
    float m = -3.4e38f;
    for (int j = 0; j < 64; ++j) m = fmaxf(m, lg[t][j]);
    float s = 0.f;
    for (int j = 0; j < 64; ++j) s += expf(lg[t][j] - m);
    rm[t] = m;
    rsum[t] = s;
  }
  __syncthreads();
  for (int i = t; i < 2560; i += 256) {
    int r = i >> 6, j = i & 63;
    bdist[r][j] = logf(expf(lg[r][j] - rm[r]) / rsum[r] + 1e-8f);
  }
  __syncthreads();
  // top-5 per beam (lax.top_k: descending, ties -> lower index)
  if (t < 40) {
    float pv = 3.4e38f;
    int pi = -1;
    for (int r = 0; r < 5; ++r) {
      float bv = -3.4e38f;
      int bi = -1;
      for (int j = 0; j < 64; ++j) {
        float v = bdist[t][j];
        bool lessprev = (v < pv) || (v == pv && j > pi);
        if (lessprev && v > bv) { bv = v; bi = j; }
      }
      bd[t][r] = bv; bc[t][r] = bi; pv = bv; pi = bi;
    }
  }
  __syncthreads();
  // per-batch merge of 25 candidates (stable argsort of -next_liks)
  if (t < 8) {
    float pv = 3.4e38f;
    int pi = -1;
    for (int r = 0; r < 5; ++r) {
      float bv = -3.4e38f;
      int bi = -1;
      for (int idx = 0; idx < 25; ++idx) {
        int kb = idx / 5, j = idx % 5;
        float v = bd[t * 5 + kb][j] + oll[t * 5 + kb];
        bool lessprev = (v < pv) || (v == pv && idx > pi);
        if (lessprev && v > bv) { bv = v; bi = idx; }
      }
      int kb = bi / 5, j = bi % 5;
      int tok = bc[t * 5 + kb][j];
      int bbn = t * 5 + r;
      nts[bbn] = tok;
      oldx[bbn] = t * 5 + kb;
      nll[bbn] = (tok == 2) ? (bv - 100000.0f) : bv;  // END penalty
      pv = bv; pi = bi;
    }
  }
  __syncthreads();
  // write back reordered state
  for (int i = t; i < 1280; i += 256) {
    int bb = i >> 5, j = i & 31;
    int v = oseq[oldx[bb]][j];
    if (j == ti + 1) v = nts[bb];
    bseqs[i] = v;
  }
  int r1 = 8 + ti;
  for (int i = t; i < 1600; i += 256) {
    int bb = i / 40, j = i % 40;
    ptr[i] = (j <= r1) ? optr[oldx[bb]][j] : bb;
  }
  if (t < 40) blls[t] = nll[t];
}

// ---------------- final output ----------------
__global__ void k_out(const int* __restrict__ bseqs, const float* __restrict__ blls,
                      float* __restrict__ out) {
  int t = blockIdx.x * 256 + threadIdx.x;
  if (t < 1280) out[t] = (float)bseqs[t];
  else if (t < 1320) out[t] = blls[t - 1280];
}

// ---------------- host ----------------
extern "C" void kernel_launch(void* const* d_in, const int* in_sizes, int n_in,
                              void* d_out, int out_size, void* d_ws, size_t ws_size,
                              hipStream_t stream) {
  const float* voxels = (const float*)d_in[0];
  const float* ck1 = (const float*)d_in[1];
  const float* cb1 = (const float*)d_in[2];
  const float* ck2 = (const float*)d_in[3];
  const float* cb2 = (const float*)d_in[4];
  const float* ck3 = (const float*)d_in[5];
  const float* cb3 = (const float*)d_in[6];
  const float* ck4 = (const float*)d_in[7];
  const float* cb4 = (const float*)d_in[8];
  const float* ck5 = (const float*)d_in[9];
  const float* cb5 = (const float*)d_in[10];
  const float* tok_emb = (const float*)d_in[11];
  const float* pos_emb = (const float*)d_in[12];
  const float* Wqkv = (const float*)d_in[13];
  const float* Wo = (const float*)d_in[14];
  const float* ln1s = (const float*)d_in[15];
  const float* ln1b = (const float*)d_in[16];
  const float* ln2s = (const float*)d_in[17];
  const float* ln2b = (const float*)d_in[18];
  const float* Wff1 = (const float*)d_in[19];
  const float* bff1 = (const float*)d_in[20];
  const float* Wff2 = (const float*)d_in[21];
  const float* bff2 = (const float*)d_in[22];
  const float* hW1 = (const float*)d_in[23];
  const float* hb1 = (const float*)d_in[24];
  const float* hW2 = (const float*)d_in[25];
  const float* hb2 = (const float*)d_in[26];

  float* ws = (float*)d_ws;
  // conv chain buffers (c1 region later aliased by decode buffers)
  float* c1 = ws;                       // 8,388,608 f
  float* c2 = c1 + 8388608;             // 2,097,152 f
  float* c3 = c2 + 2097152;             //   524,288 f
  float* c4 = c3 + 524288;              //   131,072 f
  float* codes = c4 + 131072;           //    16,384 f
  // decode region aliases c1 (conv1 output dead by then)
  float* Kc = ws;                       // 4*40*40*256 = 1,638,400 f
  float* Vc = Kc + 1638400;             // 1,638,400 f
  float* logits = Vc + 1638400;         // 2,560 f
  float* blls = logits + 2560;          // 40 f
  int* bseqs = (int*)(blls + 40);       // 1,280 i
  int* ptr = bseqs + 1280;              // 1,600 i

  conv_v1<1, 32, 32, 128><<<8 * 32 * 128, 256, 0, stream>>>(voxels, ck1, cb1, c1);
  conv_v1<32, 64, 16, 16><<<8 * 64 * 16, 256, 0, stream>>>(c1, ck2, cb2, c2);
  conv_v1<64, 128, 8, 2><<<8 * 128 * 2, 256, 0, stream>>>(c2, ck3, cb3, c3);
  conv_v2<<<8 * 256, 64, 0, stream>>>(c3, ck4, cb4, c4);
  conv_v3<<<8 * 8, 256, 0, stream>>>(c4, ck5, cb5, codes);

  k_init<<<7, 256, 0, stream>>>(bseqs, blls, ptr);
  for (int ti = 0; ti < 31; ++ti) {
    k_step<<<40, 256, 0, stream>>>(ti, codes, Kc, Vc, logits, bseqs, ptr, tok_emb,
                                   pos_emb, Wqkv, Wo, ln1s, ln1b, ln2s, ln2b, Wff1,
                                   bff1, Wff2, bff2, hW1, hb1, hW2, hb2);
    k_beam<<<1, 256, 0, stream>>>(ti, logits, bseqs, blls, ptr);
  }
  k_out<<<6, 256, 0, stream>>>(bseqs, blls, (float*)d_out);
}

// Round 2
// 13859.602 us; speedup vs baseline: 1.5362x; 1.5362x over previous
//
#include <hip/hip_runtime.h>
#include <math.h>

// ---------------- model constants ----------------
// HD=256 NL=4 NH=8 DH=32 MP=8 MS=32 T=40 ES=64 BATCH=8 BEAMS=5 BB=40
// START=1 END=2 MIN_LL_PEN=-100000

// ---------------- block reductions ----------------
__device__ __forceinline__ float blockSum256(float v, float* red) {
#pragma unroll
  for (int off = 32; off >= 1; off >>= 1) v += __shfl_xor(v, off);
  __syncthreads();
  if ((threadIdx.x & 63) == 0) red[threadIdx.x >> 6] = v;
  __syncthreads();
  return red[0] + red[1] + red[2] + red[3];
}

// 1024-thread block sum (16 waves). All threads get the full sum.
__device__ __forceinline__ float blockSum1024(float v, float* red) {
#pragma unroll
  for (int off = 32; off >= 1; off >>= 1) v += __shfl_xor(v, off);
  __syncthreads();
  if ((threadIdx.x & 63) == 0) red[threadIdx.x >> 6] = v;
  __syncthreads();
  float s = 0.f;
#pragma unroll
  for (int i = 0; i < 16; ++i) s += red[i];
  return s;
}

// ---------------- conv kernels (unchanged this round) ----------------
template <int IC, int OC, int OD, int CHUNKS>
__global__ __launch_bounds__(256) void conv_v1(const float* __restrict__ in,
                                               const float* __restrict__ w,
                                               const float* __restrict__ bias,
                                               float* __restrict__ out) {
  constexpr int ID = OD * 2;
  constexpr int ID2 = ID * ID;
  __shared__ float wl[IC * 64];
  int bi = blockIdx.x;
  int chunk = bi % CHUNKS;
  int oc = (bi / CHUNKS) % OC;
  int b = bi / (CHUNKS * OC);
  for (int i = threadIdx.x; i < IC * 64; i += 256) wl[i] = w[oc * IC * 64 + i];
  __syncthreads();
  int s = chunk * 256 + threadIdx.x;
  if (s >= OD * OD * OD) return;
  int od = s / (OD * OD), oh = (s / OD) % OD, ow = s % OD;
  float acc = 0.f;
  for (int ic = 0; ic < IC; ++ic) {
    const float* ipb = in + (size_t)(b * IC + ic) * (ID * ID2);
    const float* wp = wl + ic * 64;
#pragma unroll
    for (int kd = 0; kd < 4; ++kd) {
      int id = od * 2 - 1 + kd;
      if ((unsigned)id < (unsigned)ID) {
#pragma unroll
        for (int kh = 0; kh < 4; ++kh) {
          int ih = oh * 2 - 1 + kh;
          if ((unsigned)ih < (unsigned)ID) {
            const float* rowp = ipb + id * ID2 + ih * ID;
#pragma unroll
            for (int kw = 0; kw < 4; ++kw) {
              int iw = ow * 2 - 1 + kw;
              if ((unsigned)iw < (unsigned)ID)
                acc = fmaf(rowp[iw], wp[kd * 16 + kh * 4 + kw], acc);
            }
          }
        }
      }
    }
  }
  acc += bias[oc];
  out[((size_t)(b * OC + oc) * OD + od) * (OD * OD) + oh * OD + ow] = fmaxf(acc, 0.f);
}

__global__ __launch_bounds__(64) void conv_v2(const float* __restrict__ in,
                                              const float* __restrict__ w,
                                              const float* __restrict__ bias,
                                              float* __restrict__ out) {
  constexpr int IC = 128, OD = 4, ID = 8, ID2 = 64;
  __shared__ float wl[IC * 64];
  int oc = blockIdx.x % 256;
  int b = blockIdx.x / 256;
  for (int i = threadIdx.x; i < IC * 64; i += 64) wl[i] = w[oc * IC * 64 + i];
  __syncthreads();
  int s = threadIdx.x;
  int od = s >> 4, oh = (s >> 2) & 3, ow = s & 3;
  float acc = 0.f;
  for (int ic = 0; ic < IC; ++ic) {
    const float* ipb = in + (size_t)(b * IC + ic) * (ID * ID2);
    const float* wp = wl + ic * 64;
#pragma unroll
    for (int kd = 0; kd < 4; ++kd) {
      int id = od * 2 - 1 + kd;
      if ((unsigned)id < (unsigned)ID) {
#pragma unroll
        for (int kh = 0; kh < 4; ++kh) {
          int ih = oh * 2 - 1 + kh;
          if ((unsigned)ih < (unsigned)ID) {
            const float* rowp = ipb + id * ID2 + ih * ID;
#pragma unroll
            for (int kw = 0; kw < 4; ++kw) {
              int iw = ow * 2 - 1 + kw;
              if ((unsigned)iw < (unsigned)ID)
                acc = fmaf(rowp[iw], wp[kd * 16 + kh * 4 + kw], acc);
            }
          }
        }
      }
    }
  }
  acc += bias[oc];
  out[((size_t)(b * 256 + oc) * OD + od) * 16 + oh * 4 + ow] = fmaxf(acc, 0.f);
}

__global__ __launch_bounds__(256) void conv_v3(const float* __restrict__ in,
                                               const float* __restrict__ w,
                                               const float* __restrict__ bias,
                                               float* __restrict__ codes) {
  __shared__ float inl[256 * 64];
  int b = blockIdx.x >> 3;
  int ocg = blockIdx.x & 7;
  for (int i = threadIdx.x; i < 256 * 64; i += 256) inl[i] = in[b * 256 * 64 + i];
  __syncthreads();
  int oc = ocg * 32 + (threadIdx.x >> 3);
  int s = threadIdx.x & 7;
  int od = s >> 2, oh = (s >> 1) & 1, ow = s & 1;
  const float* wp = w + (size_t)oc * 256 * 64;
  float acc = 0.f;
  for (int ic = 0; ic < 256; ++ic) {
    const float* ib = inl + ic * 64;
    const float* wb = wp + ic * 64;
#pragma unroll
    for (int kd = 0; kd < 4; ++kd) {
      int id = od * 2 - 1 + kd;
      if ((unsigned)id < 4u) {
#pragma unroll
        for (int kh = 0; kh < 4; ++kh) {
          int ih = oh * 2 - 1 + kh;
          if ((unsigned)ih < 4u) {
#pragma unroll
            for (int kw = 0; kw < 4; ++kw) {
              int iw = ow * 2 - 1 + kw;
              if ((unsigned)iw < 4u)
                acc = fmaf(ib[id * 16 + ih * 4 + iw], wb[kd * 16 + kh * 4 + kw], acc);
            }
          }
        }
      }
    }
  }
  acc += bias[oc];
  codes[(b * 8 + s) * 256 + oc] = fmaxf(acc, 0.f);
}

// ---------------- decode state init ----------------
__global__ void k_init(int* __restrict__ bseqs, float* __restrict__ blls,
                       int* __restrict__ ptr) {
  int t = blockIdx.x * 256 + threadIdx.x;
  if (t < 1280) bseqs[t] = ((t & 31) == 0) ? 1 : 0;
  if (t < 40) blls[t] = (t % 5 == 0) ? 0.f : -100000.0f;
  if (t < 1600) ptr[t] = t / 40;
}

// ---------------- transformer step: 1024 threads, 4-way k-split ----------------
__global__ __launch_bounds__(1024) void k_step(
    int ti, const float* __restrict__ codes, float* __restrict__ Kc,
    float* __restrict__ Vc, float* __restrict__ logits,
    const int* __restrict__ bseqs, const int* __restrict__ ptr,
    const float* __restrict__ tok_emb, const float* __restrict__ pos_emb,
    const float* __restrict__ Wqkv, const float* __restrict__ Wo,
    const float* __restrict__ ln1s, const float* __restrict__ ln1b,
    const float* __restrict__ ln2s, const float* __restrict__ ln2b,
    const float* __restrict__ Wff1, const float* __restrict__ bff1,
    const float* __restrict__ Wff2, const float* __restrict__ bff2,
    const float* __restrict__ hW1, const float* __restrict__ hb1,
    const float* __restrict__ hW2, const float* __restrict__ hb2) {
  const int bb = blockIdx.x;
  const int b = bb / 5;
  const int tid = threadIdx.x;
  const int col = tid & 255;
  const int ks = tid >> 8;  // 0..3
  const int r1 = 8 + ti;
  const int r0 = (ti == 0) ? 0 : r1;
  const int NR = r1 - r0 + 1;  // 9 at prefill, else 1

  __shared__ float xs[9][256];
  __shared__ float qs[9][256];
  __shared__ float hs[256];
  __shared__ float aos[256];
  __shared__ float f1s[1024];
  __shared__ float pbuf[4][1024];
  __shared__ float scs[8][48];
  __shared__ float red[16];
  __shared__ int ips[40];

  if (tid < 40) ips[tid] = ptr[bb * 40 + tid];
  for (int ri = 0; ri < NR; ++ri) {
    int row = r0 + ri;
    if (tid < 256) {
      float v;
      if (row < 8) {
        v = codes[(b * 8 + row) * 256 + tid];
      } else {
        int tok = bseqs[bb * 32 + (row - 8)];
        v = tok_emb[tok * 256 + tid];
      }
      xs[ri][tid] = v + pos_emb[row * 256 + tid];
    }
  }
  __syncthreads();

  for (int l = 0; l < 4; ++l) {
    for (int ri = 0; ri < NR; ++ri) {
      int row = r0 + ri;
      // ---- LN1 ----
      float xv = xs[ri][col];
      float mean = blockSum1024(xv, red) * (1.f / 1024.f);
      float dv = xv - mean;
      float var = blockSum1024(dv * dv, red) * (1.f / 1024.f);
      float rsd = 1.f / sqrtf(var + 1e-5f);
      if (ks == 0) hs[col] = dv * rsd * ln1s[l * 256 + col] + ln1b[l * 256 + col];
      __syncthreads();
      // ---- QKV matvec (k-split) ----
      {
        const float* wb = Wqkv + (size_t)l * 196608 + (size_t)(ks * 64) * 768;
        float a0 = 0.f, a1 = 0.f, a2 = 0.f;
#pragma unroll 8
        for (int k = 0; k < 64; ++k) {
          float hk = hs[ks * 64 + k];
          const float* wr = wb + k * 768;
          a0 = fmaf(hk, wr[col], a0);
          a1 = fmaf(hk, wr[256 + col], a1);
          a2 = fmaf(hk, wr[512 + col], a2);
        }
        pbuf[ks][col] = a0;
        pbuf[ks][col + 256] = a1;
        pbuf[ks][col + 512] = a2;
      }
      __syncthreads();
      if (tid < 768) {
        float s = pbuf[0][tid] + pbuf[1][tid] + pbuf[2][tid] + pbuf[3][tid];
        if (tid < 256)
          qs[ri][tid] = s;
        else if (tid < 512)
          Kc[((size_t)((l * 40 + bb) * 40 + row)) * 256 + (tid - 256)] = s;
        else
          Vc[((size_t)((l * 40 + bb) * 40 + row)) * 256 + (tid - 512)] = s;
      }
      __syncthreads();
      // ---- attention scores: thread (h = tid>>7, j = tid&127) ----
      {
        int h = tid >> 7, j = tid & 127;
        if (j <= row) {
          const float* kp = Kc + ((size_t)((l * 40 + ips[j]) * 40 + j)) * 256 + h * 32;
          float s = 0.f;
#pragma unroll
          for (int dd = 0; dd < 32; ++dd) s = fmaf(qs[ri][h * 32 + dd], kp[dd], s);
          scs[h][j] = s * 0.17677669529663687f;  // 1/sqrt(32)
        }
      }
      __syncthreads();
      // ---- softmax + PV (j-loop split over ks) ----
      {
        int hh = col >> 5;
        float m = -3.4e38f;
        for (int jj = 0; jj <= row; ++jj) m = fmaxf(m, scs[hh][jj]);
        float ssum = 0.f;
        for (int jj = 0; jj <= row; ++jj) ssum += expf(scs[hh][jj] - m);
        float o = 0.f;
        for (int jj = ks; jj <= row; jj += 4) {
          float p = expf(scs[hh][jj] - m) / ssum;
          o = fmaf(p, Vc[((size_t)((l * 40 + ips[jj]) * 40 + jj)) * 256 + col], o);
        }
        pbuf[ks][col] = o;
      }
      __syncthreads();
      if (tid < 256) aos[tid] = pbuf[0][tid] + pbuf[1][tid] + pbuf[2][tid] + pbuf[3][tid];
      __syncthreads();
      // ---- Wo proj + residual ----
      {
        const float* wb = Wo + (size_t)l * 65536 + (size_t)(ks * 64) * 256;
        float a = 0.f;
#pragma unroll 8
        for (int k = 0; k < 64; ++k) a = fmaf(aos[ks * 64 + k], wb[k * 256 + col], a);
        pbuf[ks][col] = a;
      }
      __syncthreads();
      if (tid < 256)
        xs[ri][tid] = xs[ri][tid] + pbuf[0][tid] + pbuf[1][tid] + pbuf[2][tid] + pbuf[3][tid];
      __syncthreads();
      // ---- LN2 ----
      float xv2 = xs[ri][col];
      float mean2 = blockSum1024(xv2, red) * (1.f / 1024.f);
      float dv2 = xv2 - mean2;
      float var2 = blockSum1024(dv2 * dv2, red) * (1.f / 1024.f);
      float rsd2 = 1.f / sqrtf(var2 + 1e-5f);
      if (ks == 0) hs[col] = dv2 * rsd2 * ln2s[l * 256 + col] + ln2b[l * 256 + col];
      __syncthreads();
      // ---- FF1 (1024 outputs, k-split) ----
      {
        const float* wb = Wff1 + (size_t)l * 262144 + (size_t)(ks * 64) * 1024;
        float c0 = 0.f, c1 = 0.f, c2 = 0.f, c3 = 0.f;
#pragma unroll 8
        for (int k = 0; k < 64; ++k) {
          float hk = hs[ks * 64 + k];
          const float* wr = wb + k * 1024;
          c0 = fmaf(hk, wr[col], c0);
          c1 = fmaf(hk, wr[256 + col], c1);
          c2 = fmaf(hk, wr[512 + col], c2);
          c3 = fmaf(hk, wr[768 + col], c3);
        }
        pbuf[ks][col] = c0;
        pbuf[ks][col + 256] = c1;
        pbuf[ks][col + 512] = c2;
        pbuf[ks][col + 768] = c3;
      }
      __syncthreads();
      f1s[tid] = fmaxf(pbuf[0][tid] + pbuf[1][tid] + pbuf[2][tid] + pbuf[3][tid] +
                           bff1[l * 1024 + tid],
                       0.f);
      __syncthreads();
      // ---- FF2 (256 outputs, k=1024 split 4x256) ----
      {
        const float* wb = Wff2 + (size_t)l * 262144 + (size_t)(ks * 256) * 256;
        float e0 = 0.f, e1 = 0.f;
#pragma unroll 8
        for (int k = 0; k < 256; k += 2) {
          e0 = fmaf(f1s[ks * 256 + k], wb[k * 256 + col], e0);
          e1 = fmaf(f1s[ks * 256 + k + 1], wb[(k + 1) * 256 + col], e1);
        }
        pbuf[ks][col] = e0 + e1;
      }
      __syncthreads();
      if (tid < 256)
        xs[ri][tid] = xs[ri][tid] + pbuf[0][tid] + pbuf[1][tid] + pbuf[2][tid] +
                      pbuf[3][tid] + bff2[l * 256 + tid];
      __syncthreads();
    }
  }

  // ---- head on last row ----
  {
    int ri = NR - 1;
    const float* wb = hW1 + (size_t)(ks * 64) * 256;
    float a = 0.f;
#pragma unroll 8
    for (int k = 0; k < 64; ++k) a = fmaf(xs[ri][ks * 64 + k], wb[k * 256 + col], a);
    pbuf[ks][col] = a;
    __syncthreads();
    if (tid < 256)
      f1s[tid] = fmaxf(pbuf[0][tid] + pbuf[1][tid] + pbuf[2][tid] + pbuf[3][tid] + hb1[tid],
                       0.f);
    __syncthreads();
    // hW2: 64 outputs, k=256 split 16x16
    int ks2 = tid >> 6, c2 = tid & 63;
    const float* w2 = hW2 + (size_t)(ks2 * 16) * 64;
    float g = 0.f;
#pragma unroll
    for (int k = 0; k < 16; ++k) g = fmaf(f1s[ks2 * 16 + k], w2[k * 64 + c2], g);
    pbuf[0][tid] = g;
    __syncthreads();
    if (tid < 64) {
      float s = 0.f;
#pragma unroll
      for (int i = 0; i < 16; ++i) s += pbuf[0][i * 64 + tid];
      logits[bb * 64 + tid] = s + hb2[tid];
    }
  }
}

// ---------------- beam update (single WG, exact tie semantics) ----------------
__global__ __launch_bounds__(256) void k_beam(int ti, const float* __restrict__ logits,
                                              int* __restrict__ bseqs,
                                              float* __restrict__ blls,
                                              int* __restrict__ ptr) {
  __shared__ float lg[40][64];
  __shared__ float bdist[40][64];
  __shared__ float rm[40], rsum[40];
  __shared__ float bd[40][5];
  __shared__ int bc[40][5];
  __shared__ float oll[40], nll[40];
  __shared__ int nts[40], oldx[40];
  __shared__ int oseq[40][32];
  __shared__ int optr[40][40];
  int t = threadIdx.x;
  for (int i = t; i < 2560; i += 256) ((float*)lg)[i] = logits[i];
  for (int i = t; i < 1280; i += 256) ((int*)oseq)[i] = bseqs[i];
  for (int i = t; i < 1600; i += 256) ((int*)optr)[i] = ptr[i];
  if (t < 40) oll[t] = blls[t];
  __syncthreads();
  if (t < 40) {
    float m = -3.4e38f;
    for (int j = 0; j < 64; ++j) m = fmaxf(m, lg[t][j]);
    float s = 0.f;
    for (int j = 0; j < 64; ++j) s += expf(lg[t][j] - m);
    rm[t] = m;
    rsum[t] = s;
  }
  __syncthreads();
  for (int i = t; i < 2560; i += 256) {
    int r = i >> 6, j = i & 63;
    bdist[r][j] = logf(expf(lg[r][j] - rm[r]) / rsum[r] + 1e-8f);
  }
  __syncthreads();
  if (t < 40) {
    float pv = 3.4e38f;
    int pi = -1;
    for (int r = 0; r < 5; ++r) {
      float bv = -3.4e38f;
      int bi = -1;
      for (int j = 0; j < 64; ++j) {
        float v = bdist[t][j];
        bool lessprev = (v < pv) || (v == pv && j > pi);
        if (lessprev && v > bv) { bv = v; bi = j; }
      }
      bd[t][r] = bv; bc[t][r] = bi; pv = bv; pi = bi;
    }
  }
  __syncthreads();
  if (t < 8) {
    float pv = 3.4e38f;
    int pi = -1;
    for (int r = 0; r < 5; ++r) {
      float bv = -3.4e38f;
      int bi = -1;
      for (int idx = 0; idx < 25; ++idx) {
        int kb = idx / 5, j = idx % 5;
        float v = bd[t * 5 + kb][j] + oll[t * 5 + kb];
        bool lessprev = (v < pv) || (v == pv && idx > pi);
        if (lessprev && v > bv) { bv = v; bi = idx; }
      }
      int kb = bi / 5, j = bi % 5;
      int tok = bc[t * 5 + kb][j];
      int bbn = t * 5 + r;
      nts[bbn] = tok;
      oldx[bbn] = t * 5 + kb;
      nll[bbn] = (tok == 2) ? (bv - 100000.0f) : bv;
      pv = bv; pi = bi;
    }
  }
  __syncthreads();
  for (int i = t; i < 1280; i += 256) {
    int bb = i >> 5, j = i & 31;
    int v = oseq[oldx[bb]][j];
    if (j == ti + 1) v = nts[bb];
    bseqs[i] = v;
  }
  int r1 = 8 + ti;
  for (int i = t; i < 1600; i += 256) {
    int bb = i / 40, j = i % 40;
    ptr[i] = (j <= r1) ? optr[oldx[bb]][j] : bb;
  }
  if (t < 40) blls[t] = nll[t];
}

// ---------------- final output ----------------
__global__ void k_out(const int* __restrict__ bseqs, const float* __restrict__ blls,
                      float* __restrict__ out) {
  int t = blockIdx.x * 256 + threadIdx.x;
  if (t < 1280) out[t] = (float)bseqs[t];
  else if (t < 1320) out[t] = blls[t - 1280];
}

// ---------------- host ----------------
extern "C" void kernel_launch(void* const* d_in, const int* in_sizes, int n_in,
                              void* d_out, int out_size, void* d_ws, size_t ws_size,
                              hipStream_t stream) {
  const float* voxels = (const float*)d_in[0];
  const float* ck1 = (const float*)d_in[1];
  const float* cb1 = (const float*)d_in[2];
  const float* ck2 = (const float*)d_in[3];
  const float* cb2 = (const float*)d_in[4];
  const float* ck3 = (const float*)d_in[5];
  const float* cb3 = (const float*)d_in[6];
  const float* ck4 = (const float*)d_in[7];
  const float* cb4 = (const float*)d_in[8];
  const float* ck5 = (const float*)d_in[9];
  const float* cb5 = (const float*)d_in[10];
  const float* tok_emb = (const float*)d_in[11];
  const float* pos_emb = (const float*)d_in[12];
  const float* Wqkv = (const float*)d_in[13];
  const float* Wo = (const float*)d_in[14];
  const float* ln1s = (const float*)d_in[15];
  const float* ln1b = (const float*)d_in[16];
  const float* ln2s = (const float*)d_in[17];
  const float* ln2b = (const float*)d_in[18];
  const float* Wff1 = (const float*)d_in[19];
  const float* bff1 = (const float*)d_in[20];
  const float* Wff2 = (const float*)d_in[21];
  const float* bff2 = (const float*)d_in[22];
  const float* hW1 = (const float*)d_in[23];
  const float* hb1 = (const float*)d_in[24];
  const float* hW2 = (const float*)d_in[25];
  const float* hb2 = (const float*)d_in[26];

  float* ws = (float*)d_ws;
  float* c1 = ws;
  float* c2 = c1 + 8388608;
  float* c3 = c2 + 2097152;
  float* c4 = c3 + 524288;
  float* codes = c4 + 131072;
  float* Kc = ws;
  float* Vc = Kc + 1638400;
  float* logits = Vc + 1638400;
  float* blls = logits + 2560;
  int* bseqs = (int*)(blls + 40);
  int* ptr = bseqs + 1280;

  conv_v1<1, 32, 32, 128><<<8 * 32 * 128, 256, 0, stream>>>(voxels, ck1, cb1, c1);
  conv_v1<32, 64, 16, 16><<<8 * 64 * 16, 256, 0, stream>>>(c1, ck2, cb2, c2);
  conv_v1<64, 128, 8, 2><<<8 * 128 * 2, 256, 0, stream>>>(c2, ck3, cb3, c3);
  conv_v2<<<8 * 256, 64, 0, stream>>>(c3, ck4, cb4, c4);
  conv_v3<<<8 * 8, 256, 0, stream>>>(c4, ck5, cb5, codes);

  k_init<<<7, 256, 0, stream>>>(bseqs, blls, ptr);
  for (int ti = 0; ti < 31; ++ti) {
    k_step<<<40, 1024, 0, stream>>>(ti, codes, Kc, Vc, logits, bseqs, ptr, tok_emb,
                                    pos_emb, Wqkv, Wo, ln1s, ln1b, ln2s, ln2b, Wff1,
                                    bff1, Wff2, bff2, hW1, hb1, hW2, hb2);
    k_beam<<<1, 256, 0, stream>>>(ti, logits, bseqs, blls, ptr);
  }
  k_out<<<6, 256, 0, stream>>>(bseqs, blls, (float*)d_out);
}